// Round 7
// baseline (2643.373 us; speedup 1.0000x reference)
//
#include <hip/hip_runtime.h>

#define SCALE 0.95f

// ---------- Kernel 0: weight transposes ------------------------------------
// w1t: [ci*9+k][co16]   ewt: [e][k][ci][co16]   lwt: [k][ci][co8]
__global__ __launch_bounds__(256) void k_prep(
    const float* __restrict__ w1, const float* __restrict__ ew,
    const float* __restrict__ lwg, float* __restrict__ w1t,
    float* __restrict__ ewt, float* __restrict__ lwt) {
  int idx = blockIdx.x * 256 + threadIdx.x;
  if (idx < 432) {                       // w1 [16co][3ci][9k]
    int co = idx / 27, r = idx - co * 27;
    w1t[r * 16 + co] = w1[idx];
  } else if (idx < 432 + 13824) {        // ew [6e][16co][16ci][9k]
    int i = idx - 432;
    int e = i / 2304, r = i - e * 2304;
    int co = r / 144, s = r - co * 144;
    int ci = s / 9, k = s - ci * 9;
    ewt[((e * 9 + k) * 16 + ci) * 16 + co] = ew[i];
  } else if (idx < 432 + 13824 + 1152) { // lwg [8co][16ci][9k]
    int i = idx - 432 - 13824;
    int co = i / 144, s = i - co * 144;
    int ci = s / 9, k = s - ci * 9;
    lwt[(k * 16 + ci) * 8 + co] = lwg[i];
  }
}

// ---------- Kernel 1: whole network, one block per sample -------------------
// LDS h: pixel-major, padded 18x18 pixels, 20-float pixel stride.
// R6 lesson: full conv unroll hoisted ~36 b128 loads -> VGPR 132, just past
// the 128 occupancy quantum -> 2 blocks/CU. dy-loop unroll-1 keeps <=12 b128
// in flight; (256,2) caps at ~128 as a backstop (empirical: arg N -> ~256/N).
__global__ __launch_bounds__(256, 2) void k_all(
    const float* __restrict__ x, const float* __restrict__ w1t,
    const float* __restrict__ b1, const float* __restrict__ gw,
    const float* __restrict__ ewt, const float* __restrict__ eb,
    const float* __restrict__ lwt, const float* __restrict__ lbg,
    const float* __restrict__ f1w, const float* __restrict__ f1b,
    const float* __restrict__ f2w, const float* __restrict__ f2b,
    float* __restrict__ out) {
  const int b = blockIdx.x;
  const int t = threadIdx.x;
  __shared__ float lbuf[6480];          // x-tile [3][34][35] first, then h
  __shared__ double wred[2][4][6];
  __shared__ float pool[128];
  __shared__ float fred[16][8];
  __shared__ float f1v[16];

  // ---- stage x (row-major, stride 35, zero halo ring) ----
  for (int i = t; i < 396; i += 256) {
    int ci = i / 132, r = i - ci * 132;
    int yy, xx;
    if (r < 34)       { yy = 0;      xx = r; }
    else if (r < 68)  { yy = 33;     xx = r - 34; }
    else if (r < 100) { yy = r - 67; xx = 0; }
    else              { yy = r - 99; xx = 33; }
    lbuf[ci * 1190 + yy * 35 + xx] = 0.f;
  }
  {
    const float4* xb = (const float4*)(x + (size_t)b * 3072);
#pragma unroll
    for (int k = 0; k < 3; ++k) {
      int i = t + k * 256;
      float4 v = xb[i];
      int e4 = i * 4;
      int ci = e4 >> 10, rem = e4 & 1023, iy = rem >> 5, ix = rem & 31;
      float* d = &lbuf[ci * 1190 + (iy + 1) * 35 + (ix + 1)];
      d[0] = v.x; d[1] = v.y; d[2] = v.z; d[3] = v.w;
    }
  }
  __syncthreads();
  // ---- first conv 3->16 s2 p1 + ReLU ----
  const int y = t >> 4, xp = t & 15;
  float acc[16] = {};
#pragma unroll 1
  for (int ci = 0; ci < 3; ++ci) {
    const float* base = &lbuf[ci * 1190 + (2 * y) * 35 + 2 * xp];
    const float* wci = w1t + ci * 144;
#pragma unroll
    for (int dy = 0; dy < 3; ++dy)
#pragma unroll
      for (int dx = 0; dx < 3; ++dx) {
        float f = base[dy * 35 + dx];
        const float* wt = wci + (dy * 3 + dx) * 16;  // uniform -> SGPR
#pragma unroll
        for (int c = 0; c < 16; ++c) acc[c] += f * wt[c];
      }
  }
#pragma unroll
  for (int c = 0; c < 16; ++c) {
    float v = acc[c] + b1[c];
    acc[c] = v > 0.f ? v : 0.f;
  }
  __syncthreads();  // x reads done; lbuf becomes pixel-major h

  const int own = ((y + 1) * 18 + (xp + 1)) * 20;
  const float* rdbase = &lbuf[(y * 18 + xp) * 20];  // window (dy,dx) at +dy*360+dx*20

#pragma unroll 1
  for (int it = 0; it < 4; ++it) {
    if (it == 0 && t < 68) {  // zero halo pixels once
      int yy, xx;
      if (t < 18)      { yy = 0;      xx = t; }
      else if (t < 36) { yy = 17;     xx = t - 18; }
      else if (t < 52) { yy = t - 35; xx = 0; }
      else             { yy = t - 51; xx = 17; }
      float4* z = (float4*)&lbuf[(yy * 18 + xx) * 20];
      float4 zz = make_float4(0.f, 0.f, 0.f, 0.f);
      z[0] = zz; z[1] = zz; z[2] = zz; z[3] = zz;
    }
    // stage own pixel (4x ds_write_b128)
    {
      float4* op = (float4*)&lbuf[own];
      op[0] = make_float4(acc[0], acc[1], acc[2], acc[3]);
      op[1] = make_float4(acc[4], acc[5], acc[6], acc[7]);
      op[2] = make_float4(acc[8], acc[9], acc[10], acc[11]);
      op[3] = make_float4(acc[12], acc[13], acc[14], acc[15]);
    }
    // gate from registers: thread t owns flat = ci*256 + t
    {
      double s0 = 0, s1 = 0, s2 = 0, s3 = 0, s4 = 0, s5 = 0;
      const float* gwt = gw + t;
#pragma unroll
      for (int ci = 0; ci < 16; ++ci) {
        double a = (double)acc[ci];
        int o = ci * 256;
        s0 += a * (double)gwt[o];
        s1 += a * (double)gwt[o + 4096];
        s2 += a * (double)gwt[o + 8192];
        s3 += a * (double)gwt[o + 12288];
        s4 += a * (double)gwt[o + 16384];
        s5 += a * (double)gwt[o + 20480];
      }
#pragma unroll
      for (int off = 32; off > 0; off >>= 1) {
        s0 += __shfl_down(s0, off);
        s1 += __shfl_down(s1, off);
        s2 += __shfl_down(s2, off);
        s3 += __shfl_down(s3, off);
        s4 += __shfl_down(s4, off);
        s5 += __shfl_down(s5, off);
      }
      if ((t & 63) == 0) {
        double* wr = wred[it & 1][t >> 6];
        wr[0] = s0; wr[1] = s1; wr[2] = s2; wr[3] = s3; wr[4] = s4; wr[5] = s5;
      }
    }
    __syncthreads();  // staged h + wred visible
    int sel = 0;
    {
      double best = -1.0e300;
      const double (*wr)[6] = wred[it & 1];
#pragma unroll
      for (int e = 0; e < 6; ++e) {
        double v = wr[0][e] + wr[1][e] + wr[2][e] + wr[3][e];
        if (v > best) { best = v; sel = e; }  // strict >: first index on ties
      }
    }
    const int e_s = __builtin_amdgcn_readfirstlane(sel);
    // ---- expert conv 16->16 s1 p1; dy rows rolled, offsets folded ----
    float nacc[16] = {};
    const float* wb = ewt + e_s * 2304;  // [k][ci][co16]
#pragma unroll 1
    for (int dy = 0; dy < 3; ++dy) {
      const float* brow = rdbase + dy * 360;
      const float* wrow = wb + dy * 768;
#pragma unroll
      for (int dx = 0; dx < 3; ++dx) {
        const float4* np = (const float4*)(brow + dx * 20);
        const float* wk = wrow + dx * 256;
#pragma unroll
        for (int cg = 0; cg < 4; ++cg) {
          float4 in4 = np[cg];
          const float* wp = wk + cg * 64;
#pragma unroll
          for (int co = 0; co < 16; ++co) nacc[co] += in4.x * wp[co];
#pragma unroll
          for (int co = 0; co < 16; ++co) nacc[co] += in4.y * wp[16 + co];
#pragma unroll
          for (int co = 0; co < 16; ++co) nacc[co] += in4.z * wp[32 + co];
#pragma unroll
          for (int co = 0; co < 16; ++co) nacc[co] += in4.w * wp[48 + co];
        }
      }
    }
    const float* ebp = eb + e_s * 16;  // uniform
#pragma unroll
    for (int c = 0; c < 16; ++c) {
      float v = nacc[c] + ebp[c];
      v = v > 0.f ? v : 0.f;
      acc[c] = SCALE * v;
    }
    __syncthreads();  // conv reads done before next stage overwrites lbuf
  }
  // ---- tail: stage final h, last conv 16->8 s2 p1, pool, fc1, fc2 ----
  {
    float4* op = (float4*)&lbuf[own];
    op[0] = make_float4(acc[0], acc[1], acc[2], acc[3]);
    op[1] = make_float4(acc[4], acc[5], acc[6], acc[7]);
    op[2] = make_float4(acc[8], acc[9], acc[10], acc[11]);
    op[3] = make_float4(acc[12], acc[13], acc[14], acc[15]);
  }
  __syncthreads();
  const int q2 = __builtin_amdgcn_readfirstlane(t >> 6);  // co-pair (uniform)
  const int p = t & 63;
  const int oy = p >> 3, ox = p & 7;
  float a0 = 0.f, a1 = 0.f;
  {
    const float* tbase = &lbuf[((2 * oy) * 18 + 2 * ox) * 20];
#pragma unroll 1
    for (int dy = 0; dy < 3; ++dy) {
      const float* brow = tbase + dy * 360;
      const float* wrow = lwt + dy * 384 + q2 * 2;  // [k][ci][co8]
#pragma unroll
      for (int dx = 0; dx < 3; ++dx) {
        const float4* np = (const float4*)(brow + dx * 20);
        const float* wk = wrow + dx * 128;
#pragma unroll
        for (int cg = 0; cg < 4; ++cg) {
          float4 in4 = np[cg];
          const float* wp = wk + cg * 32;
          a0 += in4.x * wp[0];      a1 += in4.x * wp[1];
          a0 += in4.y * wp[8];      a1 += in4.y * wp[9];
          a0 += in4.z * wp[16];     a1 += in4.z * wp[17];
          a0 += in4.w * wp[24];     a1 += in4.w * wp[25];
        }
      }
    }
  }
  // ReLU + 2x2 maxpool via shuffles (lane = oy*8+ox): ^1 -> ox, ^8 -> oy
#pragma unroll
  for (int j = 0; j < 2; ++j) {
    int co = q2 * 2 + j;
    float v = (j == 0 ? a0 : a1) + lbg[co];
    v = v > 0.f ? v : 0.f;
    float m = fmaxf(v, __shfl_xor(v, 1));
    m = fmaxf(m, __shfl_xor(m, 8));
    if (((oy | ox) & 1) == 0) pool[co * 16 + (oy >> 1) * 4 + (ox >> 1)] = m;
  }
  __syncthreads();
  if (t < 128) {  // fc1: 16 rows x 8 segments of 16
    const int r = t & 15, sg = t >> 4;
    const float* wr = f1w + r * 128 + sg * 16;
    const float* pp = pool + sg * 16;
    float a = 0.f;
#pragma unroll
    for (int j = 0; j < 16; ++j) a += pp[j] * wr[j];
    fred[r][sg] = a;
  }
  __syncthreads();
  if (t < 16) {
    float a = f1b[t];
#pragma unroll
    for (int sg = 0; sg < 8; ++sg) a += fred[t][sg];
    f1v[t] = a > 0.f ? a : 0.f;
  }
  __syncthreads();
  if (t < 10) {
    float a = f2b[t];
#pragma unroll
    for (int j = 0; j < 16; ++j) a += f1v[j] * f2w[t * 16 + j];
    out[(size_t)b * 10 + t] = a;
  }
}

extern "C" void kernel_launch(void* const* d_in, const int* in_sizes, int n_in,
                              void* d_out, int out_size, void* d_ws, size_t ws_size,
                              hipStream_t stream) {
  const float* x   = (const float*)d_in[0];
  const float* w1  = (const float*)d_in[1];
  const float* b1  = (const float*)d_in[2];
  const float* ew  = (const float*)d_in[3];
  const float* eb  = (const float*)d_in[4];
  const float* gw  = (const float*)d_in[5];
  const float* lwg = (const float*)d_in[6];
  const float* lbg = (const float*)d_in[7];
  const float* f1w = (const float*)d_in[8];
  const float* f1b = (const float*)d_in[9];
  const float* f2w = (const float*)d_in[10];
  const float* f2b = (const float*)d_in[11];

  float* w1t = (float*)d_ws;            // 432
  float* ewt = w1t + 432;               // 13824
  float* lwt = ewt + 13824;             // 1152
  float* outp = (float*)d_out;

  k_prep<<<61, 256, 0, stream>>>(w1, ew, lwg, w1t, ewt, lwt);
  k_all<<<8192, 256, 0, stream>>>(x, w1t, b1, gw, ewt, eb, lwt, lbg,
                                  f1w, f1b, f2w, f2b, outp);
}

// Round 8
// 509.403 us; speedup vs baseline: 5.1892x; 5.1892x over previous
//
#include <hip/hip_runtime.h>

#define SCALE 0.95f

// ---------- Kernel 0: weight transposes ------------------------------------
// w1t: [ci*9+k][co16]   ewt: [e][k][ci][co16]   lwt: [k][ci][co8]
__global__ __launch_bounds__(256) void k_prep(
    const float* __restrict__ w1, const float* __restrict__ ew,
    const float* __restrict__ lwg, float* __restrict__ w1t,
    float* __restrict__ ewt, float* __restrict__ lwt) {
  int idx = blockIdx.x * 256 + threadIdx.x;
  if (idx < 432) {                       // w1 [16co][3ci][9k]
    int co = idx / 27, r = idx - co * 27;
    w1t[r * 16 + co] = w1[idx];
  } else if (idx < 432 + 13824) {        // ew [6e][16co][16ci][9k]
    int i = idx - 432;
    int e = i / 2304, r = i - e * 2304;
    int co = r / 144, s = r - co * 144;
    int ci = s / 9, k = s - ci * 9;
    ewt[((e * 9 + k) * 16 + ci) * 16 + co] = ew[i];
  } else if (idx < 432 + 13824 + 1152) { // lwg [8co][16ci][9k]
    int i = idx - 432 - 13824;
    int co = i / 144, s = i - co * 144;
    int ci = s / 9, k = s - ci * 9;
    lwt[(k * 16 + ci) * 8 + co] = lwg[i];
  }
}

// ---------- Kernel 1: whole network, one block per sample -------------------
// LDS h: pixel-major, padded 18x18 pixels, 20-float pixel stride (b128 reads
// hit all 32 banks at 2 lanes/bank).
// HARD LESSON (R4/R5/R7): any min-waves arg in __launch_bounds__ squeezes the
// allocator below natural pressure -> spills (scratch OR v_accvgpr VALU bloat).
// Natural allocation only; pressure is bounded STRUCTURALLY: rolled dy-loop
// (<=12 b128 hoisted), gate ci-loop unroll 4 (<=24 gw loads hoisted).
__global__ __launch_bounds__(256) void k_all(
    const float* __restrict__ x, const float* __restrict__ w1t,
    const float* __restrict__ b1, const float* __restrict__ gw,
    const float* __restrict__ ewt, const float* __restrict__ eb,
    const float* __restrict__ lwt, const float* __restrict__ lbg,
    const float* __restrict__ f1w, const float* __restrict__ f1b,
    const float* __restrict__ f2w, const float* __restrict__ f2b,
    float* __restrict__ out) {
  const int b = blockIdx.x;
  const int t = threadIdx.x;
  __shared__ float lbuf[6480];          // x-tile [3][34][35] first, then h
  __shared__ double wred[2][4][6];
  __shared__ float pool[128];
  __shared__ float fred[16][8];
  __shared__ float f1v[16];

  // ---- stage x (row-major, stride 35, zero halo ring) ----
  for (int i = t; i < 396; i += 256) {
    int ci = i / 132, r = i - ci * 132;
    int yy, xx;
    if (r < 34)       { yy = 0;      xx = r; }
    else if (r < 68)  { yy = 33;     xx = r - 34; }
    else if (r < 100) { yy = r - 67; xx = 0; }
    else              { yy = r - 99; xx = 33; }
    lbuf[ci * 1190 + yy * 35 + xx] = 0.f;
  }
  {
    const float4* xb = (const float4*)(x + (size_t)b * 3072);
#pragma unroll
    for (int k = 0; k < 3; ++k) {
      int i = t + k * 256;
      float4 v = xb[i];
      int e4 = i * 4;
      int ci = e4 >> 10, rem = e4 & 1023, iy = rem >> 5, ix = rem & 31;
      float* d = &lbuf[ci * 1190 + (iy + 1) * 35 + (ix + 1)];
      d[0] = v.x; d[1] = v.y; d[2] = v.z; d[3] = v.w;
    }
  }
  __syncthreads();
  // ---- first conv 3->16 s2 p1 + ReLU ----
  const int y = t >> 4, xp = t & 15;
  float acc[16] = {};
#pragma unroll 1
  for (int ci = 0; ci < 3; ++ci) {
    const float* base = &lbuf[ci * 1190 + (2 * y) * 35 + 2 * xp];
    const float* wci = w1t + ci * 144;
#pragma unroll
    for (int dy = 0; dy < 3; ++dy)
#pragma unroll
      for (int dx = 0; dx < 3; ++dx) {
        float f = base[dy * 35 + dx];
        const float* wt = wci + (dy * 3 + dx) * 16;  // uniform -> SGPR
#pragma unroll
        for (int c = 0; c < 16; ++c) acc[c] += f * wt[c];
      }
  }
#pragma unroll
  for (int c = 0; c < 16; ++c) {
    float v = acc[c] + b1[c];
    acc[c] = v > 0.f ? v : 0.f;
  }
  __syncthreads();  // x reads done; lbuf becomes pixel-major h

  const int own = ((y + 1) * 18 + (xp + 1)) * 20;
  const float* rdbase = &lbuf[(y * 18 + xp) * 20];  // tap (dy,dx) at +dy*360+dx*20

#pragma unroll 1
  for (int it = 0; it < 4; ++it) {
    if (it == 0 && t < 68) {  // zero halo pixels once
      int yy, xx;
      if (t < 18)      { yy = 0;      xx = t; }
      else if (t < 36) { yy = 17;     xx = t - 18; }
      else if (t < 52) { yy = t - 35; xx = 0; }
      else             { yy = t - 51; xx = 17; }
      float4* z = (float4*)&lbuf[(yy * 18 + xx) * 20];
      float4 zz = make_float4(0.f, 0.f, 0.f, 0.f);
      z[0] = zz; z[1] = zz; z[2] = zz; z[3] = zz;
    }
    // stage own pixel (4x ds_write_b128)
    {
      float4* op = (float4*)&lbuf[own];
      op[0] = make_float4(acc[0], acc[1], acc[2], acc[3]);
      op[1] = make_float4(acc[4], acc[5], acc[6], acc[7]);
      op[2] = make_float4(acc[8], acc[9], acc[10], acc[11]);
      op[3] = make_float4(acc[12], acc[13], acc[14], acc[15]);
    }
    // gate from registers: thread t owns flat = ci*256 + t. unroll 4 bounds
    // hoisted gw loads to 24 (full unroll hoisted up to 96 -> VGPR peak).
    {
      double s0 = 0, s1 = 0, s2 = 0, s3 = 0, s4 = 0, s5 = 0;
      const float* gwt = gw + t;
#pragma unroll 4
      for (int ci = 0; ci < 16; ++ci) {
        double a = (double)acc[ci];
        int o = ci * 256;
        s0 += a * (double)gwt[o];
        s1 += a * (double)gwt[o + 4096];
        s2 += a * (double)gwt[o + 8192];
        s3 += a * (double)gwt[o + 12288];
        s4 += a * (double)gwt[o + 16384];
        s5 += a * (double)gwt[o + 20480];
      }
#pragma unroll
      for (int off = 32; off > 0; off >>= 1) {
        s0 += __shfl_down(s0, off);
        s1 += __shfl_down(s1, off);
        s2 += __shfl_down(s2, off);
        s3 += __shfl_down(s3, off);
        s4 += __shfl_down(s4, off);
        s5 += __shfl_down(s5, off);
      }
      if ((t & 63) == 0) {
        double* wr = wred[it & 1][t >> 6];
        wr[0] = s0; wr[1] = s1; wr[2] = s2; wr[3] = s3; wr[4] = s4; wr[5] = s5;
      }
    }
    __syncthreads();  // staged h + wred visible
    int sel = 0;
    {
      double best = -1.0e300;
      const double (*wr)[6] = wred[it & 1];
#pragma unroll
      for (int e = 0; e < 6; ++e) {
        double v = wr[0][e] + wr[1][e] + wr[2][e] + wr[3][e];
        if (v > best) { best = v; sel = e; }  // strict >: first index on ties
      }
    }
    const int e_s = __builtin_amdgcn_readfirstlane(sel);
    // ---- expert conv 16->16 s1 p1; dy rows rolled (bounds hoist to 12 b128)
    float nacc[16] = {};
    const float* wb = ewt + e_s * 2304;  // [k][ci][co16]
#pragma unroll 1
    for (int dy = 0; dy < 3; ++dy) {
      const float* brow = rdbase + dy * 360;
      const float* wrow = wb + dy * 768;
#pragma unroll
      for (int dx = 0; dx < 3; ++dx) {
        const float4* np = (const float4*)(brow + dx * 20);
        const float* wk = wrow + dx * 256;
#pragma unroll
        for (int cg = 0; cg < 4; ++cg) {
          float4 in4 = np[cg];
          const float* wp = wk + cg * 64;
#pragma unroll
          for (int co = 0; co < 16; ++co) nacc[co] += in4.x * wp[co];
#pragma unroll
          for (int co = 0; co < 16; ++co) nacc[co] += in4.y * wp[16 + co];
#pragma unroll
          for (int co = 0; co < 16; ++co) nacc[co] += in4.z * wp[32 + co];
#pragma unroll
          for (int co = 0; co < 16; ++co) nacc[co] += in4.w * wp[48 + co];
        }
      }
    }
    const float* ebp = eb + e_s * 16;  // uniform
#pragma unroll
    for (int c = 0; c < 16; ++c) {
      float v = nacc[c] + ebp[c];
      v = v > 0.f ? v : 0.f;
      acc[c] = SCALE * v;
    }
    __syncthreads();  // conv reads done before next stage overwrites lbuf
  }
  // ---- tail: stage final h, last conv 16->8 s2 p1, pool, fc1, fc2 ----
  {
    float4* op = (float4*)&lbuf[own];
    op[0] = make_float4(acc[0], acc[1], acc[2], acc[3]);
    op[1] = make_float4(acc[4], acc[5], acc[6], acc[7]);
    op[2] = make_float4(acc[8], acc[9], acc[10], acc[11]);
    op[3] = make_float4(acc[12], acc[13], acc[14], acc[15]);
  }
  __syncthreads();
  const int q2 = __builtin_amdgcn_readfirstlane(t >> 6);  // co-pair (uniform)
  const int p = t & 63;
  const int oy = p >> 3, ox = p & 7;
  float a0 = 0.f, a1 = 0.f;
  {
    const float* tbase = &lbuf[((2 * oy) * 18 + 2 * ox) * 20];
#pragma unroll 1
    for (int dy = 0; dy < 3; ++dy) {
      const float* brow = tbase + dy * 360;
      const float* wrow = lwt + dy * 384 + q2 * 2;  // [k][ci][co8]
#pragma unroll
      for (int dx = 0; dx < 3; ++dx) {
        const float4* np = (const float4*)(brow + dx * 20);
        const float* wk = wrow + dx * 128;
#pragma unroll
        for (int cg = 0; cg < 4; ++cg) {
          float4 in4 = np[cg];
          const float* wp = wk + cg * 32;
          a0 += in4.x * wp[0];      a1 += in4.x * wp[1];
          a0 += in4.y * wp[8];      a1 += in4.y * wp[9];
          a0 += in4.z * wp[16];     a1 += in4.z * wp[17];
          a0 += in4.w * wp[24];     a1 += in4.w * wp[25];
        }
      }
    }
  }
  // ReLU + 2x2 maxpool via shuffles (lane = oy*8+ox): ^1 -> ox, ^8 -> oy
#pragma unroll
  for (int j = 0; j < 2; ++j) {
    int co = q2 * 2 + j;
    float v = (j == 0 ? a0 : a1) + lbg[co];
    v = v > 0.f ? v : 0.f;
    float m = fmaxf(v, __shfl_xor(v, 1));
    m = fmaxf(m, __shfl_xor(m, 8));
    if (((oy | ox) & 1) == 0) pool[co * 16 + (oy >> 1) * 4 + (ox >> 1)] = m;
  }
  __syncthreads();
  if (t < 128) {  // fc1: 16 rows x 8 segments of 16
    const int r = t & 15, sg = t >> 4;
    const float* wr = f1w + r * 128 + sg * 16;
    const float* pp = pool + sg * 16;
    float a = 0.f;
#pragma unroll
    for (int j = 0; j < 16; ++j) a += pp[j] * wr[j];
    fred[r][sg] = a;
  }
  __syncthreads();
  if (t < 16) {
    float a = f1b[t];
#pragma unroll
    for (int sg = 0; sg < 8; ++sg) a += fred[t][sg];
    f1v[t] = a > 0.f ? a : 0.f;
  }
  __syncthreads();
  if (t < 10) {
    float a = f2b[t];
#pragma unroll
    for (int j = 0; j < 16; ++j) a += f1v[j] * f2w[t * 16 + j];
    out[(size_t)b * 10 + t] = a;
  }
}

extern "C" void kernel_launch(void* const* d_in, const int* in_sizes, int n_in,
                              void* d_out, int out_size, void* d_ws, size_t ws_size,
                              hipStream_t stream) {
  const float* x   = (const float*)d_in[0];
  const float* w1  = (const float*)d_in[1];
  const float* b1  = (const float*)d_in[2];
  const float* ew  = (const float*)d_in[3];
  const float* eb  = (const float*)d_in[4];
  const float* gw  = (const float*)d_in[5];
  const float* lwg = (const float*)d_in[6];
  const float* lbg = (const float*)d_in[7];
  const float* f1w = (const float*)d_in[8];
  const float* f1b = (const float*)d_in[9];
  const float* f2w = (const float*)d_in[10];
  const float* f2b = (const float*)d_in[11];

  float* w1t = (float*)d_ws;            // 432
  float* ewt = w1t + 432;               // 13824
  float* lwt = ewt + 13824;             // 1152
  float* outp = (float*)d_out;

  k_prep<<<61, 256, 0, stream>>>(w1, ew, lwg, w1t, ewt, lwt);
  k_all<<<8192, 256, 0, stream>>>(x, w1t, b1, gw, ewt, eb, lwt, lbg,
                                  f1w, f1b, f2w, f2b, outp);
}

// Round 9
// 501.901 us; speedup vs baseline: 5.2667x; 1.0149x over previous
//
#include <hip/hip_runtime.h>

#define SCALE 0.95f

// ---------- Kernel 0: weight transposes ------------------------------------
// w1t: [ci*9+k][co16]   ewt: [e][k][ci][co16]   lwt: [k][ci][co8]
__global__ __launch_bounds__(256) void k_prep(
    const float* __restrict__ w1, const float* __restrict__ ew,
    const float* __restrict__ lwg, float* __restrict__ w1t,
    float* __restrict__ ewt, float* __restrict__ lwt) {
  int idx = blockIdx.x * 256 + threadIdx.x;
  if (idx < 432) {                       // w1 [16co][3ci][9k]
    int co = idx / 27, r = idx - co * 27;
    w1t[r * 16 + co] = w1[idx];
  } else if (idx < 432 + 13824) {        // ew [6e][16co][16ci][9k]
    int i = idx - 432;
    int e = i / 2304, r = i - e * 2304;
    int co = r / 144, s = r - co * 144;
    int ci = s / 9, k = s - ci * 9;
    ewt[((e * 9 + k) * 16 + ci) * 16 + co] = ew[i];
  } else if (idx < 432 + 13824 + 1152) { // lwg [8co][16ci][9k]
    int i = idx - 432 - 13824;
    int co = i / 144, s = i - co * 144;
    int ci = s / 9, k = s - ci * 9;
    lwt[(k * 16 + ci) * 8 + co] = lwg[i];
  }
}

// ---------- Kernel 1: whole network, one block per sample -------------------
// LDS h: pixel-major, padded 18x18 pixels, 20-float pixel stride (b128 reads
// hit all 32 banks at 2 lanes/bank).
// HARD LESSON (R4/R5/R7): never pass a min-waves arg -> allocator squeeze ->
// spills (scratch OR v_accvgpr VALU bloat). Natural allocation only.
// R8: VGPR 44, LDS 27.6KB -> LDS-bound at 5 blocks/CU. R9: alias tail-only
// buffers (pool/fred/f1v) into h's dead halo row -> 26.3KB -> 6 blocks/CU;
// fully unroll expert conv (budget: VGPR <= 85 keeps 6 blocks).
__global__ __launch_bounds__(256) void k_all(
    const float* __restrict__ x, const float* __restrict__ w1t,
    const float* __restrict__ b1, const float* __restrict__ gw,
    const float* __restrict__ ewt, const float* __restrict__ eb,
    const float* __restrict__ lwt, const float* __restrict__ lbg,
    const float* __restrict__ f1w, const float* __restrict__ f1b,
    const float* __restrict__ f2w, const float* __restrict__ f2b,
    float* __restrict__ out) {
  const int b = blockIdx.x;
  const int t = threadIdx.x;
  __shared__ float lbuf[6480];          // x-tile [3][34][35] first, then h
  __shared__ double wred[2][4][6];
  // tail-only buffers alias h's halo row 0 (dead after last conv reads):
  float* pool = lbuf;                   // 128 floats
  float* fred = lbuf + 128;             // 128 floats  [r*8+sg]
  float* f1v  = lbuf + 256;             // 16 floats

  // ---- stage x (row-major, stride 35, zero halo ring) ----
  for (int i = t; i < 396; i += 256) {
    int ci = i / 132, r = i - ci * 132;
    int yy, xx;
    if (r < 34)       { yy = 0;      xx = r; }
    else if (r < 68)  { yy = 33;     xx = r - 34; }
    else if (r < 100) { yy = r - 67; xx = 0; }
    else              { yy = r - 99; xx = 33; }
    lbuf[ci * 1190 + yy * 35 + xx] = 0.f;
  }
  {
    const float4* xb = (const float4*)(x + (size_t)b * 3072);
#pragma unroll
    for (int k = 0; k < 3; ++k) {
      int i = t + k * 256;
      float4 v = xb[i];
      int e4 = i * 4;
      int ci = e4 >> 10, rem = e4 & 1023, iy = rem >> 5, ix = rem & 31;
      float* d = &lbuf[ci * 1190 + (iy + 1) * 35 + (ix + 1)];
      d[0] = v.x; d[1] = v.y; d[2] = v.z; d[3] = v.w;
    }
  }
  __syncthreads();
  // ---- first conv 3->16 s2 p1 + ReLU ----
  const int y = t >> 4, xp = t & 15;
  float acc[16] = {};
#pragma unroll 1
  for (int ci = 0; ci < 3; ++ci) {
    const float* base = &lbuf[ci * 1190 + (2 * y) * 35 + 2 * xp];
    const float* wci = w1t + ci * 144;
#pragma unroll
    for (int dy = 0; dy < 3; ++dy)
#pragma unroll
      for (int dx = 0; dx < 3; ++dx) {
        float f = base[dy * 35 + dx];
        const float* wt = wci + (dy * 3 + dx) * 16;  // uniform -> SGPR
#pragma unroll
        for (int c = 0; c < 16; ++c) acc[c] += f * wt[c];
      }
  }
#pragma unroll
  for (int c = 0; c < 16; ++c) {
    float v = acc[c] + b1[c];
    acc[c] = v > 0.f ? v : 0.f;
  }
  __syncthreads();  // x reads done; lbuf becomes pixel-major h

  const int own = ((y + 1) * 18 + (xp + 1)) * 20;
  const float* rdbase = &lbuf[(y * 18 + xp) * 20];  // tap (dy,dx) at +dy*360+dx*20

#pragma unroll 1
  for (int it = 0; it < 4; ++it) {
    if (it == 0 && t < 68) {  // zero halo pixels once
      int yy, xx;
      if (t < 18)      { yy = 0;      xx = t; }
      else if (t < 36) { yy = 17;     xx = t - 18; }
      else if (t < 52) { yy = t - 35; xx = 0; }
      else             { yy = t - 51; xx = 17; }
      float4* z = (float4*)&lbuf[(yy * 18 + xx) * 20];
      float4 zz = make_float4(0.f, 0.f, 0.f, 0.f);
      z[0] = zz; z[1] = zz; z[2] = zz; z[3] = zz;
    }
    // stage own pixel (4x ds_write_b128)
    {
      float4* op = (float4*)&lbuf[own];
      op[0] = make_float4(acc[0], acc[1], acc[2], acc[3]);
      op[1] = make_float4(acc[4], acc[5], acc[6], acc[7]);
      op[2] = make_float4(acc[8], acc[9], acc[10], acc[11]);
      op[3] = make_float4(acc[12], acc[13], acc[14], acc[15]);
    }
    // gate from registers: thread t owns flat = ci*256 + t. unroll 4 bounds
    // hoisted gw loads to 24 (full unroll hoisted up to 96 -> VGPR peak).
    {
      double s0 = 0, s1 = 0, s2 = 0, s3 = 0, s4 = 0, s5 = 0;
      const float* gwt = gw + t;
#pragma unroll 4
      for (int ci = 0; ci < 16; ++ci) {
        double a = (double)acc[ci];
        int o = ci * 256;
        s0 += a * (double)gwt[o];
        s1 += a * (double)gwt[o + 4096];
        s2 += a * (double)gwt[o + 8192];
        s3 += a * (double)gwt[o + 12288];
        s4 += a * (double)gwt[o + 16384];
        s5 += a * (double)gwt[o + 20480];
      }
#pragma unroll
      for (int off = 32; off > 0; off >>= 1) {
        s0 += __shfl_down(s0, off);
        s1 += __shfl_down(s1, off);
        s2 += __shfl_down(s2, off);
        s3 += __shfl_down(s3, off);
        s4 += __shfl_down(s4, off);
        s5 += __shfl_down(s5, off);
      }
      if ((t & 63) == 0) {
        double* wr = wred[it & 1][t >> 6];
        wr[0] = s0; wr[1] = s1; wr[2] = s2; wr[3] = s3; wr[4] = s4; wr[5] = s5;
      }
    }
    __syncthreads();  // staged h + wred visible
    int sel = 0;
    {
      double best = -1.0e300;
      const double (*wr)[6] = wred[it & 1];
#pragma unroll
      for (int e = 0; e < 6; ++e) {
        double v = wr[0][e] + wr[1][e] + wr[2][e] + wr[3][e];
        if (v > best) { best = v; sel = e; }  // strict >: first index on ties
      }
    }
    const int e_s = __builtin_amdgcn_readfirstlane(sel);
    // ---- expert conv 16->16 s1 p1; FULLY unrolled (rdbase + immediates) ----
    float nacc[16] = {};
    const float* wb = ewt + e_s * 2304;  // [k][ci][co16]
#pragma unroll
    for (int dy = 0; dy < 3; ++dy) {
      const float* brow = rdbase + dy * 360;
      const float* wrow = wb + dy * 768;
#pragma unroll
      for (int dx = 0; dx < 3; ++dx) {
        const float4* np = (const float4*)(brow + dx * 20);
        const float* wk = wrow + dx * 256;
#pragma unroll
        for (int cg = 0; cg < 4; ++cg) {
          float4 in4 = np[cg];
          const float* wp = wk + cg * 64;
#pragma unroll
          for (int co = 0; co < 16; ++co) nacc[co] += in4.x * wp[co];
#pragma unroll
          for (int co = 0; co < 16; ++co) nacc[co] += in4.y * wp[16 + co];
#pragma unroll
          for (int co = 0; co < 16; ++co) nacc[co] += in4.z * wp[32 + co];
#pragma unroll
          for (int co = 0; co < 16; ++co) nacc[co] += in4.w * wp[48 + co];
        }
      }
    }
    const float* ebp = eb + e_s * 16;  // uniform
#pragma unroll
    for (int c = 0; c < 16; ++c) {
      float v = nacc[c] + ebp[c];
      v = v > 0.f ? v : 0.f;
      acc[c] = SCALE * v;
    }
    __syncthreads();  // conv reads done before next stage overwrites lbuf
  }
  // ---- tail: stage final h, last conv 16->8 s2 p1, pool, fc1, fc2 ----
  {
    float4* op = (float4*)&lbuf[own];
    op[0] = make_float4(acc[0], acc[1], acc[2], acc[3]);
    op[1] = make_float4(acc[4], acc[5], acc[6], acc[7]);
    op[2] = make_float4(acc[8], acc[9], acc[10], acc[11]);
    op[3] = make_float4(acc[12], acc[13], acc[14], acc[15]);
  }
  __syncthreads();
  const int q2 = __builtin_amdgcn_readfirstlane(t >> 6);  // co-pair (uniform)
  const int p = t & 63;
  const int oy = p >> 3, ox = p & 7;
  float a0 = 0.f, a1 = 0.f;
  {
    const float* tbase = &lbuf[((2 * oy) * 18 + 2 * ox) * 20];
#pragma unroll 1
    for (int dy = 0; dy < 3; ++dy) {
      const float* brow = tbase + dy * 360;
      const float* wrow = lwt + dy * 384 + q2 * 2;  // [k][ci][co8]
#pragma unroll
      for (int dx = 0; dx < 3; ++dx) {
        const float4* np = (const float4*)(brow + dx * 20);
        const float* wk = wrow + dx * 128;
#pragma unroll
        for (int cg = 0; cg < 4; ++cg) {
          float4 in4 = np[cg];
          const float* wp = wk + cg * 32;
          a0 += in4.x * wp[0];      a1 += in4.x * wp[1];
          a0 += in4.y * wp[8];      a1 += in4.y * wp[9];
          a0 += in4.z * wp[16];     a1 += in4.z * wp[17];
          a0 += in4.w * wp[24];     a1 += in4.w * wp[25];
        }
      }
    }
  }
  __syncthreads();  // ALL window reads (incl. halo) done before pool aliases it
  // ReLU + 2x2 maxpool via shuffles (lane = oy*8+ox): ^1 -> ox, ^8 -> oy
#pragma unroll
  for (int j = 0; j < 2; ++j) {
    int co = q2 * 2 + j;
    float v = (j == 0 ? a0 : a1) + lbg[co];
    v = v > 0.f ? v : 0.f;
    float m = fmaxf(v, __shfl_xor(v, 1));
    m = fmaxf(m, __shfl_xor(m, 8));
    if (((oy | ox) & 1) == 0) pool[co * 16 + (oy >> 1) * 4 + (ox >> 1)] = m;
  }
  __syncthreads();
  if (t < 128) {  // fc1: 16 rows x 8 segments of 16
    const int r = t & 15, sg = t >> 4;
    const float* wr = f1w + r * 128 + sg * 16;
    const float* pp = pool + sg * 16;
    float a = 0.f;
#pragma unroll
    for (int j = 0; j < 16; ++j) a += pp[j] * wr[j];
    fred[r * 8 + sg] = a;
  }
  __syncthreads();
  if (t < 16) {
    float a = f1b[t];
#pragma unroll
    for (int sg = 0; sg < 8; ++sg) a += fred[t * 8 + sg];
    f1v[t] = a > 0.f ? a : 0.f;
  }
  __syncthreads();
  if (t < 10) {
    float a = f2b[t];
#pragma unroll
    for (int j = 0; j < 16; ++j) a += f1v[j] * f2w[t * 16 + j];
    out[(size_t)b * 10 + t] = a;
  }
}

extern "C" void kernel_launch(void* const* d_in, const int* in_sizes, int n_in,
                              void* d_out, int out_size, void* d_ws, size_t ws_size,
                              hipStream_t stream) {
  const float* x   = (const float*)d_in[0];
  const float* w1  = (const float*)d_in[1];
  const float* b1  = (const float*)d_in[2];
  const float* ew  = (const float*)d_in[3];
  const float* eb  = (const float*)d_in[4];
  const float* gw  = (const float*)d_in[5];
  const float* lwg = (const float*)d_in[6];
  const float* lbg = (const float*)d_in[7];
  const float* f1w = (const float*)d_in[8];
  const float* f1b = (const float*)d_in[9];
  const float* f2w = (const float*)d_in[10];
  const float* f2b = (const float*)d_in[11];

  float* w1t = (float*)d_ws;            // 432
  float* ewt = w1t + 432;               // 13824
  float* lwt = ewt + 13824;             // 1152
  float* outp = (float*)d_out;

  k_prep<<<61, 256, 0, stream>>>(w1, ew, lwg, w1t, ewt, lwt);
  k_all<<<8192, 256, 0, stream>>>(x, w1t, b1, gw, ewt, eb, lwt, lbg,
                                  f1w, f1b, f2w, f2b, outp);
}